// Round 7
// baseline (528.837 us; speedup 1.0000x reference)
//
#include <hip/hip_runtime.h>
#include <hip/hip_bf16.h>
#include <math.h>

typedef __bf16 bf16;
typedef __bf16 bf16x8 __attribute__((ext_vector_type(8)));
typedef short bf16x4s __attribute__((ext_vector_type(4)));
typedef float f32x4 __attribute__((ext_vector_type(4)));

#define DIM 768
#define NH 12
#define HD 64
#define HID 3072
#define BB 4
#define SS 2048
#define QPRESCALE 0.18033688011112042f /* (1/8) * log2(e) */

#define MFMA(a, b, c) __builtin_amdgcn_mfma_f32_16x16x32_bf16(a, b, c, 0, 0, 0)
#define MFMA16(a, b, c) \
  __builtin_amdgcn_mfma_f32_16x16x16bf16_1k(a, b, c, 0, 0, 0)

__device__ __forceinline__ void gld16(const void* g, void* l) {
  __builtin_amdgcn_global_load_lds(
      (const __attribute__((address_space(1))) void*)g,
      (__attribute__((address_space(3))) void*)l, 16, 0, 0);
}

__device__ __forceinline__ unsigned pk2(float a, float b) {
  union {
    bf16 h[2];
    unsigned u;
  } t;
  t.h[0] = (bf16)a;
  t.h[1] = (bf16)b;
  return t.u;
}

// ---------------- fused weight cast + transpose: fp32 [R][C] -> bf16 [C][R] -
__global__ __launch_bounds__(256) void castT_all_kernel(
    const float* __restrict__ s0, bf16* __restrict__ d0,
    const float* __restrict__ s1, bf16* __restrict__ d1,
    const float* __restrict__ s2, bf16* __restrict__ d2,
    const float* __restrict__ s3, bf16* __restrict__ d3) {
  __shared__ float tile[32][33];
  int id = blockIdx.x;
  const float* in;
  bf16* out;
  int R, C, loc;
  if (id < 1728) { in = s0; out = d0; R = 768; C = 2304; loc = id; }
  else if (id < 2304) { in = s1; out = d1; R = 768; C = 768; loc = id - 1728; }
  else if (id < 4608) { in = s2; out = d2; R = 768; C = 3072; loc = id - 2304; }
  else { in = s3; out = d3; R = 3072; C = 768; loc = id - 4608; }
  const int cb = C >> 5;
  const int c0 = (loc % cb) * 32, r0 = (loc / cb) * 32;
  const int tx = threadIdx.x & 31, ty = threadIdx.x >> 5;  // ty 0..7
#pragma unroll
  for (int i = 0; i < 32; i += 8)
    tile[ty + i][tx] = in[(size_t)(r0 + ty + i) * C + c0 + tx];
  __syncthreads();
#pragma unroll
  for (int i = 0; i < 32; i += 8)
    out[(size_t)(c0 + ty + i) * R + r0 + tx] = (bf16)tile[tx][ty + i];
}

// ---------------- mask int32 [B][1][S][S] -> bitmask [B][S][S/32] ----------
__global__ __launch_bounds__(256) void maskbits_kernel(
    const int* __restrict__ mask, unsigned* __restrict__ bits) {
  const int i = blockIdx.x * 256 + threadIdx.x;
  unsigned long long m = __ballot(mask[i] != 0);
  const int lane = threadIdx.x & 63;
  if (lane == 0) bits[i >> 5] = (unsigned)m;
  else if (lane == 32) bits[i >> 5] = (unsigned)(m >> 32);
}

// ---------------- LayerNorm fp32 row(768) -> bf16 --------------------------
__global__ __launch_bounds__(256) void ln_kernel(
    const float* __restrict__ x, const float* __restrict__ g,
    const float* __restrict__ beta, bf16* __restrict__ out) {
  const int row = blockIdx.x, t = threadIdx.x;
  const float* xr = x + (size_t)row * DIM;
  float v0 = xr[t], v1 = xr[t + 256], v2 = xr[t + 512];
  float s = v0 + v1 + v2;
  float s2 = v0 * v0 + v1 * v1 + v2 * v2;
#pragma unroll
  for (int d = 1; d < 64; d <<= 1) {
    s += __shfl_xor(s, d);
    s2 += __shfl_xor(s2, d);
  }
  __shared__ float red[8];
  const int wv = t >> 6, lane = t & 63;
  if (lane == 0) { red[wv] = s; red[wv + 4] = s2; }
  __syncthreads();
  s = red[0] + red[1] + red[2] + red[3];
  s2 = red[4] + red[5] + red[6] + red[7];
  const float mu = s * (1.0f / DIM);
  const float var = s2 * (1.0f / DIM) - mu * mu;
  const float r = rsqrtf(var + 1e-6f);
  bf16* o = out + (size_t)row * DIM;
  o[t] = (bf16)((v0 - mu) * r * g[t] + beta[t]);
  o[t + 256] = (bf16)((v1 - mu) * r * g[t + 256] + beta[t + 256]);
  o[t + 512] = (bf16)((v2 - mu) * r * g[t + 512] + beta[t + 512]);
}

// ---------------- GEMM: A[M][K] bf16 x Bt[N][K] bf16 -> epilogue -----------
// TM=128. TN=128: 2x2 waves of 64x64. TN=64: 4x1 waves of 32x64.
// Double-buffered LDS: stage(next) issued AFTER the barrier, ONE barrier/iter;
// the syncthreads vmcnt(0) then only drains DMAs issued one compute-phase ago.
enum { EPI_QKV = 0, EPI_PROJ = 1, EPI_FFN1 = 2, EPI_FFN2 = 3 };

template <int EPI, int K, int TN>
__global__ __launch_bounds__(256) void gemm_kernel(
    const bf16* __restrict__ A, const bf16* __restrict__ Bt,
    const float* __restrict__ bias, const float* __restrict__ res,
    void* __restrict__ o0, void* __restrict__ o1, void* __restrict__ o2) {
  constexpr int MI = (TN == 128) ? 4 : 2;
  constexpr int NIT = K / 64;
  __shared__ bf16 As[2][128 * 64];
  __shared__ bf16 Bs[2][TN * 64];
  const int tid = threadIdx.x;
  const int wv = tid >> 6, lane = tid & 63;
  const int quad = lane >> 4, l15 = lane & 15;
  const int lrow = lane >> 3, lcol = lane & 7;
  const int m0 = blockIdx.y * 128, n0 = blockIdx.x * TN;
  const int wm = (TN == 128) ? (wv >> 1) * 64 : wv * 32;
  const int wn = (TN == 128) ? (wv & 1) * 64 : 0;

  f32x4 acc[MI][4] = {};

  // staging: lane -> row lrow, slot lcol ; swizzled global chunk = lcol^lrow
  const int swz = (lcol ^ lrow) * 8;
  const bf16* Ag = A + (size_t)(m0 + wv * 32 + lrow) * K + swz;
  const bf16* Bg = Bt + (size_t)(n0 + wv * (TN / 4) + lrow) * K + swz;

  auto stage = [&](int buf, int k0) {
#pragma unroll
    for (int i = 0; i < 4; i++)
      gld16(Ag + (size_t)(i * 8) * K + k0, &As[buf][(wv * 32 + i * 8) * 64]);
#pragma unroll
    for (int i = 0; i < TN / 32; i++)
      gld16(Bg + (size_t)(i * 8) * K + k0,
            &Bs[buf][(wv * (TN / 4) + i * 8) * 64]);
  };

  stage(0, 0);

  for (int it = 0; it < NIT; ++it) {
    __syncthreads();  // drains this iter's DMAs (issued one compute ago)
    if (it + 1 < NIT) stage((it + 1) & 1, (it + 1) * 64);
    const bf16* Ab = As[it & 1];
    const bf16* Bb = Bs[it & 1];
#pragma unroll
    for (int ks = 0; ks < 2; ks++) {
      bf16x8 af[MI], bfr[4];
#pragma unroll
      for (int i = 0; i < MI; i++) {
        const int ra = wm + i * 16 + l15;
        af[i] = *(const bf16x8*)&Ab[ra * 64 + ((ks * 4 + quad) ^ (ra & 7)) * 8];
      }
#pragma unroll
      for (int i = 0; i < 4; i++) {
        const int rb = wn + i * 16 + l15;
        bfr[i] =
            *(const bf16x8*)&Bb[rb * 64 + ((ks * 4 + quad) ^ (rb & 7)) * 8];
      }
#pragma unroll
      for (int mi = 0; mi < MI; mi++)
#pragma unroll
        for (int ni = 0; ni < 4; ni++)
          acc[mi][ni] = MFMA(af[mi], bfr[ni], acc[mi][ni]);
    }
  }

  // epilogue: C layout col=lane&15, row=quad*4+reg
#pragma unroll
  for (int mi = 0; mi < MI; mi++) {
#pragma unroll
    for (int ni = 0; ni < 4; ni++) {
      const int n = n0 + wn + ni * 16 + l15;
      const float bv = bias[n];
      const int mb = m0 + wm + mi * 16 + quad * 4;
      float val[4];
#pragma unroll
      for (int r = 0; r < 4; r++) val[r] = acc[mi][ni][r] + bv;
      if (EPI == EPI_QKV) {
        const int which = n / 768;
        const int nn = n - which * 768;
        const int hh = nn >> 6, d = nn & 63;
        const int bb = mb >> 11, s = mb & 2047;
        if (which == 0) {
#pragma unroll
          for (int r = 0; r < 4; r++)
            ((bf16*)o0)[((size_t)(bb * NH + hh) * SS + s + r) * HD + d] =
                (bf16)(val[r] * QPRESCALE);
        } else if (which == 1) {
#pragma unroll
          for (int r = 0; r < 4; r++)
            ((bf16*)o1)[((size_t)(bb * NH + hh) * SS + s + r) * HD + d] =
                (bf16)val[r];
        } else {
          // V transposed [bh][d][s]: 4 consecutive s -> packed 8B store
          uint2 pv;
          pv.x = pk2(val[0], val[1]);
          pv.y = pk2(val[2], val[3]);
          *(uint2*)&((bf16*)o2)[((size_t)(bb * NH + hh) * HD + d) * SS + s] = pv;
        }
      } else if (EPI == EPI_PROJ) {
#pragma unroll
        for (int r = 0; r < 4; r++)
          ((float*)o0)[(size_t)(mb + r) * DIM + n] =
              res[(size_t)(mb + r) * DIM + n] + val[r];
      } else if (EPI == EPI_FFN1) {
#pragma unroll
        for (int r = 0; r < 4; r++) {
          const float ge =
              0.5f * val[r] * (1.0f + erff(val[r] * 0.70710678118654752f));
          ((bf16*)o0)[(size_t)(mb + r) * HID + n] = (bf16)ge;
        }
      } else {  // EPI_FFN2
#pragma unroll
        for (int r = 0; r < 4; r++)
          ((float*)o0)[(size_t)(mb + r) * DIM + n] =
              res[(size_t)(mb + r) * DIM + n] + val[r];
      }
    }
  }
}

// ---------------- flash attention ------------------------------------------
// Sᵀ = MFMA(kfrag, qfrag) -> C layout (col=q, row=k) IS mfma16's B-frag
// layout, so PV needs no P movement. lsum via ones-A MFMA16 (row-sum of P).
// Mask via 16-entry LDS LUT on packed P. Double-buffered K/V staging,
// one barrier per tile, mask word prefetched one tile ahead in registers.
__global__ __launch_bounds__(256) void attn_kernel(
    const bf16* __restrict__ q, const bf16* __restrict__ k,
    const bf16* __restrict__ vT, const unsigned* __restrict__ bits,
    bf16* __restrict__ wa) {
  const int b = blockIdx.z, h = blockIdx.y, q0 = blockIdx.x * 64;
  const int tid = threadIdx.x, wv = tid >> 6, lane = tid & 63;
  const int quad = lane >> 4, l15 = lane & 15;
  const int lrow = lane >> 3, lcol = lane & 7;

  __shared__ bf16 Ks[2][64 * 64];
  __shared__ bf16 Vs[2][64 * 64];
  __shared__ unsigned lut[32];

  if (tid < 16) {
    lut[2 * tid] =
        ((tid & 1) ? 0xFFFFu : 0u) | ((tid & 2) ? 0xFFFF0000u : 0u);
    lut[2 * tid + 1] =
        ((tid & 4) ? 0xFFFFu : 0u) | ((tid & 8) ? 0xFFFF0000u : 0u);
  }

  const bf16* qbh = q + (size_t)(b * NH + h) * SS * HD;
  const bf16* kbh = k + (size_t)(b * NH + h) * SS * HD;
  const bf16* vbh = vT + (size_t)(b * NH + h) * HD * SS;

  const int sq = q0 + wv * 16 + l15;  // this lane's q row
  bf16x8 aq[2];
#pragma unroll
  for (int ks = 0; ks < 2; ks++)
    aq[ks] = *(const bf16x8*)&qbh[(size_t)sq * HD + ks * 32 + quad * 8];

  const unsigned long long* mrow =
      (const unsigned long long*)bits + (size_t)(b * SS + sq) * 32;

  f32x4 O[4] = {};
  f32x4 lm = {};
  const short oneb = 0x3F80;
  const bf16x4s onesA = {oneb, oneb, oneb, oneb};
  const int swz = (lcol ^ lrow) * 8;

  auto stageKV = [&](int buf, int s0) {
#pragma unroll
    for (int i = 0; i < 2; i++) {
      const int r = wv * 16 + i * 8 + lrow;
      gld16(&kbh[(size_t)(s0 + r) * HD + swz],
            &Ks[buf][(wv * 16 + i * 8) * 64]);
      gld16(&vbh[(size_t)r * SS + s0 + swz],
            &Vs[buf][(wv * 16 + i * 8) * 64]);
    }
  };

  stageKV(0, 0);
  unsigned long long mw = mrow[0];

  for (int t = 0; t < SS / 64; ++t) {
    __syncthreads();  // drains this tile's DMAs (issued one compute ago)
    unsigned long long mwn = 0;
    if (t + 1 < SS / 64) {
      stageKV((t + 1) & 1, (t + 1) * 64);
      mwn = mrow[t + 1];
    }
    const bf16* Kc = Ks[t & 1];
    const bf16* Vc = Vs[t & 1];
    const unsigned long long sh = mw >> (quad * 4);
    const unsigned lo32 = (unsigned)sh, hi32 = (unsigned)(sh >> 32);

#pragma unroll
    for (int ni = 0; ni < 4; ni++) {
      const int rr = ni * 16 + l15;
      const bf16x8 kf0 = *(const bf16x8*)&Kc[rr * 64 + (quad ^ (rr & 7)) * 8];
      const bf16x8 kf1 =
          *(const bf16x8*)&Kc[rr * 64 + ((4 + quad) ^ (rr & 7)) * 8];
      f32x4 a = {};
      a = MFMA(kf0, aq[0], a);
      a = MFMA(kf1, aq[1], a);
      const unsigned nib = (ni == 0)   ? (lo32 & 0xF)
                           : (ni == 1) ? ((lo32 >> 16) & 0xF)
                           : (ni == 2) ? (hi32 & 0xF)
                                       : ((hi32 >> 16) & 0xF);
      const uint2 mwrd = *(const uint2*)&lut[2 * nib];
      union {
        unsigned u[2];
        bf16x4s v;
      } pp;
      pp.u[0] = pk2(__builtin_amdgcn_exp2f(a[0]),
                    __builtin_amdgcn_exp2f(a[1])) & mwrd.x;
      pp.u[1] = pk2(__builtin_amdgcn_exp2f(a[2]),
                    __builtin_amdgcn_exp2f(a[3])) & mwrd.y;
      lm = MFMA16(onesA, pp.v, lm);
#pragma unroll
      for (int nd = 0; nd < 4; nd++) {
        const int row = nd * 16 + l15;
        const int pc = (ni * 2 + (quad >> 1)) ^ (row & 7);
        const bf16x4s vf =
            *(const bf16x4s*)&Vc[row * 64 + pc * 8 + (quad & 1) * 4];
        O[nd] = MFMA16(vf, pp.v, O[nd]);
      }
    }
    mw = mwn;
  }

  // lm[r] (any r) = full softmax denominator for q=l15
  const float rln = __builtin_amdgcn_rcpf(lm[0]);
  bf16* dst = wa + (size_t)(b * SS + sq) * DIM + h * HD + quad * 4;
#pragma unroll
  for (int nd = 0; nd < 4; nd++) {
    uint2 pv;
    pv.x = pk2(O[nd][0] * rln, O[nd][1] * rln);
    pv.y = pk2(O[nd][2] * rln, O[nd][3] * rln);
    *(uint2*)&dst[nd * 16] = pv;
  }
}

// ---------------------------------------------------------------------------
extern "C" void kernel_launch(void* const* d_in, const int* in_sizes, int n_in,
                              void* d_out, int out_size, void* d_ws,
                              size_t ws_size, hipStream_t stream) {
  const float* x = (const float*)d_in[0];
  const int* mask = (const int*)d_in[1];
  const float* w_qkv = (const float*)d_in[2];
  const float* b_qkv = (const float*)d_in[3];
  const float* w_proj = (const float*)d_in[4];
  const float* b_proj = (const float*)d_in[5];
  const float* g1 = (const float*)d_in[6];
  const float* beta1 = (const float*)d_in[7];
  const float* g2 = (const float*)d_in[8];
  const float* beta2 = (const float*)d_in[9];
  const float* w1 = (const float*)d_in[10];
  const float* b1 = (const float*)d_in[11];
  const float* w2 = (const float*)d_in[12];
  const float* b2 = (const float*)d_in[13];
  float* out = (float*)d_out;

  char* p = (char*)d_ws;
  auto alloc = [&](size_t bytes) {
    char* r = p;
    p += (bytes + 1023) & ~(size_t)1023;
    return r;
  };
  bf16* wqkvT = (bf16*)alloc((size_t)2304 * 768 * 2);
  bf16* wprojT = (bf16*)alloc((size_t)768 * 768 * 2);
  bf16* w1T = (bf16*)alloc((size_t)3072 * 768 * 2);
  bf16* w2T = (bf16*)alloc((size_t)768 * 3072 * 2);
  unsigned* bits = (unsigned*)alloc((size_t)BB * SS * 64 * 4);
  bf16* h = (bf16*)alloc((size_t)8192 * 768 * 2);
  bf16* qb = (bf16*)alloc((size_t)8192 * 768 * 2);
  bf16* kb = (bf16*)alloc((size_t)8192 * 768 * 2);
  bf16* vtb = (bf16*)alloc((size_t)8192 * 768 * 2);
  bf16* wab = (bf16*)alloc((size_t)8192 * 768 * 2);
  float* x2 = (float*)alloc((size_t)8192 * 768 * 4);
  bf16* ffn1 = (bf16*)alloc((size_t)8192 * 3072 * 2);

  // fused weight cast+transpose (one launch)
  castT_all_kernel<<<6912, 256, 0, stream>>>(w_qkv, wqkvT, w_proj, wprojT, w1,
                                             w1T, w2, w2T);
  // mask -> bits
  maskbits_kernel<<<(BB * SS * SS) / 256, 256, 0, stream>>>(mask, bits);
  // LN1
  ln_kernel<<<8192, 256, 0, stream>>>(x, g1, beta1, h);
  // QKV (V written pre-transposed, Q pre-scaled)
  gemm_kernel<EPI_QKV, 768, 128>
      <<<dim3(2304 / 128, 8192 / 128), 256, 0, stream>>>(h, wqkvT, b_qkv,
                                                         nullptr, qb, kb, vtb);
  // attention (64 q-rows per block)
  attn_kernel<<<dim3(SS / 64, NH, BB), 256, 0, stream>>>(qb, kb, vtb, bits,
                                                         wab);
  // proj + residual (TN=64 -> 768 blocks)
  gemm_kernel<EPI_PROJ, 768, 64>
      <<<dim3(768 / 64, 8192 / 128), 256, 0, stream>>>(wab, wprojT, b_proj, x,
                                                       x2, nullptr, nullptr);
  // LN2
  ln_kernel<<<8192, 256, 0, stream>>>(x2, g2, beta2, h);
  // FFN1 + GELU
  gemm_kernel<EPI_FFN1, 768, 128>
      <<<dim3(3072 / 128, 8192 / 128), 256, 0, stream>>>(h, w1T, b1, nullptr,
                                                         ffn1, nullptr,
                                                         nullptr);
  // FFN2 + residual -> out (TN=64 -> 768 blocks)
  gemm_kernel<EPI_FFN2, 3072, 64>
      <<<dim3(768 / 64, 8192 / 128), 256, 0, stream>>>(ffn1, w2T, b2, x2, out,
                                                       nullptr, nullptr);
}

// Round 8
// 505.132 us; speedup vs baseline: 1.0469x; 1.0469x over previous
//
#include <hip/hip_runtime.h>
#include <hip/hip_bf16.h>
#include <math.h>

typedef __bf16 bf16;
typedef __bf16 bf16x8 __attribute__((ext_vector_type(8)));
typedef short bf16x4s __attribute__((ext_vector_type(4)));
typedef float f32x4 __attribute__((ext_vector_type(4)));

#define DIM 768
#define NH 12
#define HD 64
#define HID 3072
#define BB 4
#define SS 2048
#define QPRESCALE 0.18033688011112042f /* (1/8) * log2(e) */

#define MFMA(a, b, c) __builtin_amdgcn_mfma_f32_16x16x32_bf16(a, b, c, 0, 0, 0)
#define MFMA16(a, b, c) \
  __builtin_amdgcn_mfma_f32_16x16x16bf16_1k(a, b, c, 0, 0, 0)

__device__ __forceinline__ void gld16(const void* g, void* l) {
  __builtin_amdgcn_global_load_lds(
      (const __attribute__((address_space(1))) void*)g,
      (__attribute__((address_space(3))) void*)l, 16, 0, 0);
}

__device__ __forceinline__ unsigned pk2(float a, float b) {
  union {
    bf16 h[2];
    unsigned u;
  } t;
  t.h[0] = (bf16)a;
  t.h[1] = (bf16)b;
  return t.u;
}

// ---------------- fused weight cast + transpose: fp32 [R][C] -> bf16 [C][R] -
__global__ __launch_bounds__(256) void castT_all_kernel(
    const float* __restrict__ s0, bf16* __restrict__ d0,
    const float* __restrict__ s1, bf16* __restrict__ d1,
    const float* __restrict__ s2, bf16* __restrict__ d2,
    const float* __restrict__ s3, bf16* __restrict__ d3) {
  __shared__ float tile[32][33];
  int id = blockIdx.x;
  const float* in;
  bf16* out;
  int R, C, loc;
  if (id < 1728) { in = s0; out = d0; R = 768; C = 2304; loc = id; }
  else if (id < 2304) { in = s1; out = d1; R = 768; C = 768; loc = id - 1728; }
  else if (id < 4608) { in = s2; out = d2; R = 768; C = 3072; loc = id - 2304; }
  else { in = s3; out = d3; R = 3072; C = 768; loc = id - 4608; }
  const int cb = C >> 5;
  const int c0 = (loc % cb) * 32, r0 = (loc / cb) * 32;
  const int tx = threadIdx.x & 31, ty = threadIdx.x >> 5;  // ty 0..7
#pragma unroll
  for (int i = 0; i < 32; i += 8)
    tile[ty + i][tx] = in[(size_t)(r0 + ty + i) * C + c0 + tx];
  __syncthreads();
#pragma unroll
  for (int i = 0; i < 32; i += 8)
    out[(size_t)(c0 + ty + i) * R + r0 + tx] = (bf16)tile[tx][ty + i];
}

// ---------------- mask int32 [B][1][S][S] -> bitmask [B][S][S/32] ----------
__global__ __launch_bounds__(256) void maskbits_kernel(
    const int* __restrict__ mask, unsigned* __restrict__ bits) {
  const int i = blockIdx.x * 256 + threadIdx.x;
  unsigned long long m = __ballot(mask[i] != 0);
  const int lane = threadIdx.x & 63;
  if (lane == 0) bits[i >> 5] = (unsigned)m;
  else if (lane == 32) bits[i >> 5] = (unsigned)(m >> 32);
}

// ---------------- LayerNorm fp32 row(768) -> bf16 --------------------------
__global__ __launch_bounds__(256) void ln_kernel(
    const float* __restrict__ x, const float* __restrict__ g,
    const float* __restrict__ beta, bf16* __restrict__ out) {
  const int row = blockIdx.x, t = threadIdx.x;
  const float* xr = x + (size_t)row * DIM;
  float v0 = xr[t], v1 = xr[t + 256], v2 = xr[t + 512];
  float s = v0 + v1 + v2;
  float s2 = v0 * v0 + v1 * v1 + v2 * v2;
#pragma unroll
  for (int d = 1; d < 64; d <<= 1) {
    s += __shfl_xor(s, d);
    s2 += __shfl_xor(s2, d);
  }
  __shared__ float red[8];
  const int wv = t >> 6, lane = t & 63;
  if (lane == 0) { red[wv] = s; red[wv + 4] = s2; }
  __syncthreads();
  s = red[0] + red[1] + red[2] + red[3];
  s2 = red[4] + red[5] + red[6] + red[7];
  const float mu = s * (1.0f / DIM);
  const float var = s2 * (1.0f / DIM) - mu * mu;
  const float r = rsqrtf(var + 1e-6f);
  bf16* o = out + (size_t)row * DIM;
  o[t] = (bf16)((v0 - mu) * r * g[t] + beta[t]);
  o[t + 256] = (bf16)((v1 - mu) * r * g[t + 256] + beta[t + 256]);
  o[t + 512] = (bf16)((v2 - mu) * r * g[t + 512] + beta[t + 512]);
}

// ---------------- GEMM: A[M][K] bf16 x Bt[N][K] bf16 -> epilogue -----------
// TM=128 fixed. TN=128: 2x2 waves of 64x64. TN=64: 4x1 waves of 32x64.
// Single-buffered (R6): dbuf's 64KB LDS cut occupancy and net-regressed (R7).
enum { EPI_QKV = 0, EPI_PROJ = 1, EPI_FFN1 = 2, EPI_FFN2 = 3 };

template <int EPI, int K, int TN>
__global__ __launch_bounds__(256) void gemm_kernel(
    const bf16* __restrict__ A, const bf16* __restrict__ Bt,
    const float* __restrict__ bias, const float* __restrict__ res,
    void* __restrict__ o0, void* __restrict__ o1, void* __restrict__ o2) {
  constexpr int MI = (TN == 128) ? 4 : 2;
  __shared__ bf16 As[128 * 64];
  __shared__ bf16 Bs[TN * 64];
  const int tid = threadIdx.x;
  const int wv = tid >> 6, lane = tid & 63;
  const int quad = lane >> 4, l15 = lane & 15;
  const int lrow = lane >> 3, lcol = lane & 7;
  const int m0 = blockIdx.y * 128, n0 = blockIdx.x * TN;
  const int wm = (TN == 128) ? (wv >> 1) * 64 : wv * 32;
  const int wn = (TN == 128) ? (wv & 1) * 64 : 0;

  f32x4 acc[MI][4] = {};

  // staging: lane -> row lrow, slot lcol ; swizzled global chunk = lcol^lrow
  const int swz = (lcol ^ lrow) * 8;
  const bf16* Ag = A + (size_t)(m0 + wv * 32 + lrow) * K + swz;
  const bf16* Bg = Bt + (size_t)(n0 + wv * (TN / 4) + lrow) * K + swz;
  bf16* Al = As + (wv * 32) * 64;
  bf16* Bl = Bs + (wv * (TN / 4)) * 64;

  for (int k0 = 0; k0 < K; k0 += 64) {
#pragma unroll
    for (int i = 0; i < 4; i++)
      gld16(Ag + (size_t)(i * 8) * K + k0, Al + i * 8 * 64);
#pragma unroll
    for (int i = 0; i < TN / 32; i++)
      gld16(Bg + (size_t)(i * 8) * K + k0, Bl + i * 8 * 64);
    __syncthreads();
#pragma unroll
    for (int ks = 0; ks < 2; ks++) {
      bf16x8 af[MI], bfr[4];
#pragma unroll
      for (int i = 0; i < MI; i++) {
        const int ra = wm + i * 16 + l15;
        af[i] = *(const bf16x8*)&As[ra * 64 + ((ks * 4 + quad) ^ (ra & 7)) * 8];
      }
#pragma unroll
      for (int i = 0; i < 4; i++) {
        const int rb = wn + i * 16 + l15;
        bfr[i] = *(const bf16x8*)&Bs[rb * 64 + ((ks * 4 + quad) ^ (rb & 7)) * 8];
      }
#pragma unroll
      for (int mi = 0; mi < MI; mi++)
#pragma unroll
        for (int ni = 0; ni < 4; ni++)
          acc[mi][ni] = MFMA(af[mi], bfr[ni], acc[mi][ni]);
    }
    __syncthreads();
  }

  // epilogue: C layout col=lane&15, row=quad*4+reg
#pragma unroll
  for (int mi = 0; mi < MI; mi++) {
#pragma unroll
    for (int ni = 0; ni < 4; ni++) {
      const int n = n0 + wn + ni * 16 + l15;
      const float bv = bias[n];
      const int mb = m0 + wm + mi * 16 + quad * 4;
      float val[4];
#pragma unroll
      for (int r = 0; r < 4; r++) val[r] = acc[mi][ni][r] + bv;
      if (EPI == EPI_QKV) {
        const int which = n / 768;
        const int nn = n - which * 768;
        const int hh = nn >> 6, d = nn & 63;
        const int bb = mb >> 11, s = mb & 2047;
        if (which == 0) {
#pragma unroll
          for (int r = 0; r < 4; r++)
            ((bf16*)o0)[((size_t)(bb * NH + hh) * SS + s + r) * HD + d] =
                (bf16)(val[r] * QPRESCALE);
        } else if (which == 1) {
#pragma unroll
          for (int r = 0; r < 4; r++)
            ((bf16*)o1)[((size_t)(bb * NH + hh) * SS + s + r) * HD + d] =
                (bf16)val[r];
        } else {
          // V transposed [bh][d][s]: 4 consecutive s -> packed 8B store
          uint2 pv;
          pv.x = pk2(val[0], val[1]);
          pv.y = pk2(val[2], val[3]);
          *(uint2*)&((bf16*)o2)[((size_t)(bb * NH + hh) * HD + d) * SS + s] = pv;
        }
      } else if (EPI == EPI_PROJ) {
#pragma unroll
        for (int r = 0; r < 4; r++)
          ((float*)o0)[(size_t)(mb + r) * DIM + n] =
              res[(size_t)(mb + r) * DIM + n] + val[r];
      } else if (EPI == EPI_FFN1) {
#pragma unroll
        for (int r = 0; r < 4; r++) {
          const float ge =
              0.5f * val[r] * (1.0f + erff(val[r] * 0.70710678118654752f));
          ((bf16*)o0)[(size_t)(mb + r) * HID + n] = (bf16)ge;
        }
      } else {  // EPI_FFN2
#pragma unroll
        for (int r = 0; r < 4; r++)
          ((float*)o0)[(size_t)(mb + r) * DIM + n] =
              res[(size_t)(mb + r) * DIM + n] + val[r];
      }
    }
  }
}

// ---------------- flash attention ------------------------------------------
// Sᵀ = MFMA(kfrag, qfrag) -> C layout (col=q, row=k) IS mfma16's B-frag
// layout, so PV needs no P movement. lsum via ones-A MFMA16 (row-sum of P).
// Mask via 16-entry LDS LUT on packed P.
// 128 q-rows per block, TWO q-fragments per wave: every wave re-reads the
// full K/V tile from LDS regardless of q-count, so more q per wave halves
// LDS-read per FLOP (the R6/R7 64-q version was LDS-pipe-bound ~60us floor).
__global__ __launch_bounds__(256) void attn_kernel(
    const bf16* __restrict__ q, const bf16* __restrict__ k,
    const bf16* __restrict__ vT, const unsigned* __restrict__ bits,
    bf16* __restrict__ wa) {
  const int b = blockIdx.z, h = blockIdx.y, q0 = blockIdx.x * 128;
  const int tid = threadIdx.x, wv = tid >> 6, lane = tid & 63;
  const int quad = lane >> 4, l15 = lane & 15;
  const int lrow = lane >> 3, lcol = lane & 7;

  __shared__ bf16 Ks[64 * 64];
  __shared__ bf16 Vs[64 * 64];
  __shared__ unsigned lut[32];

  if (tid < 16) {
    lut[2 * tid] =
        ((tid & 1) ? 0xFFFFu : 0u) | ((tid & 2) ? 0xFFFF0000u : 0u);
    lut[2 * tid + 1] =
        ((tid & 4) ? 0xFFFFu : 0u) | ((tid & 8) ? 0xFFFF0000u : 0u);
  }

  const bf16* qbh = q + (size_t)(b * NH + h) * SS * HD;
  const bf16* kbh = k + (size_t)(b * NH + h) * SS * HD;
  const bf16* vbh = vT + (size_t)(b * NH + h) * HD * SS;

  // Q fragments (B-operand for Sᵀ): q-row = q0 + wv*32 + mi*16 + l15
  bf16x8 aq[2][2];
#pragma unroll
  for (int mi = 0; mi < 2; mi++)
#pragma unroll
    for (int ks = 0; ks < 2; ks++) {
      const int s = q0 + wv * 32 + mi * 16 + l15;
      aq[mi][ks] = *(const bf16x8*)&qbh[(size_t)s * HD + ks * 32 + quad * 8];
    }

  const unsigned long long* mrow[2];
#pragma unroll
  for (int mi = 0; mi < 2; mi++)
    mrow[mi] = (const unsigned long long*)bits +
               (size_t)(b * SS + q0 + wv * 32 + mi * 16 + l15) * 32;

  f32x4 O[2][4] = {};
  f32x4 lm[2] = {};
  const short oneb = 0x3F80;
  const bf16x4s onesA = {oneb, oneb, oneb, oneb};
  const int swz = (lcol ^ lrow) * 8;

  for (int t = 0; t < SS / 64; ++t) {
    const int s0 = t * 64;
    // stage K[s0..+64][0..64] and Vᵀ[0..64][s0..+64] (XOR-chunk swizzle)
#pragma unroll
    for (int i = 0; i < 2; i++) {
      const int r = wv * 16 + i * 8 + lrow;
      gld16(&kbh[(size_t)(s0 + r) * HD + swz], &Ks[(wv * 16 + i * 8) * 64]);
      gld16(&vbh[(size_t)r * SS + s0 + swz], &Vs[(wv * 16 + i * 8) * 64]);
    }
    const unsigned long long sh0 = mrow[0][t] >> (quad * 4);
    const unsigned long long sh1 = mrow[1][t] >> (quad * 4);
    const unsigned lo0 = (unsigned)sh0, hi0 = (unsigned)(sh0 >> 32);
    const unsigned lo1 = (unsigned)sh1, hi1 = (unsigned)(sh1 >> 32);
    __syncthreads();

#pragma unroll
    for (int ni = 0; ni < 4; ni++) {
      const int rr = ni * 16 + l15;
      const bf16x8 kf0 = *(const bf16x8*)&Ks[rr * 64 + (quad ^ (rr & 7)) * 8];
      const bf16x8 kf1 =
          *(const bf16x8*)&Ks[rr * 64 + ((4 + quad) ^ (rr & 7)) * 8];
      f32x4 a0 = {}, a1 = {};
      a0 = MFMA(kf0, aq[0][0], a0);
      a0 = MFMA(kf1, aq[0][1], a0);
      a1 = MFMA(kf0, aq[1][0], a1);
      a1 = MFMA(kf1, aq[1][1], a1);
      const unsigned nib0 = (ni == 0)   ? (lo0 & 0xF)
                            : (ni == 1) ? ((lo0 >> 16) & 0xF)
                            : (ni == 2) ? (hi0 & 0xF)
                                        : ((hi0 >> 16) & 0xF);
      const unsigned nib1 = (ni == 0)   ? (lo1 & 0xF)
                            : (ni == 1) ? ((lo1 >> 16) & 0xF)
                            : (ni == 2) ? (hi1 & 0xF)
                                        : ((hi1 >> 16) & 0xF);
      const uint2 mw0 = *(const uint2*)&lut[2 * nib0];
      const uint2 mw1 = *(const uint2*)&lut[2 * nib1];
      union {
        unsigned u[2];
        bf16x4s v;
      } p0, p1;
      p0.u[0] = pk2(__builtin_amdgcn_exp2f(a0[0]),
                    __builtin_amdgcn_exp2f(a0[1])) & mw0.x;
      p0.u[1] = pk2(__builtin_amdgcn_exp2f(a0[2]),
                    __builtin_amdgcn_exp2f(a0[3])) & mw0.y;
      p1.u[0] = pk2(__builtin_amdgcn_exp2f(a1[0]),
                    __builtin_amdgcn_exp2f(a1[1])) & mw1.x;
      p1.u[1] = pk2(__builtin_amdgcn_exp2f(a1[2]),
                    __builtin_amdgcn_exp2f(a1[3])) & mw1.y;
      lm[0] = MFMA16(onesA, p0.v, lm[0]);
      lm[1] = MFMA16(onesA, p1.v, lm[1]);
#pragma unroll
      for (int nd = 0; nd < 4; nd++) {
        const int row = nd * 16 + l15;
        const int pc = (ni * 2 + (quad >> 1)) ^ (row & 7);
        const bf16x4s vf =
            *(const bf16x4s*)&Vs[row * 64 + pc * 8 + (quad & 1) * 4];
        O[0][nd] = MFMA16(vf, p0.v, O[0][nd]);
        O[1][nd] = MFMA16(vf, p1.v, O[1][nd]);
      }
    }
    __syncthreads();
  }

  // lm[mi][r] (any r) = full softmax denominator for this lane's q-row
#pragma unroll
  for (int mi = 0; mi < 2; mi++) {
    const float rln = __builtin_amdgcn_rcpf(lm[mi][0]);
    const int sq = q0 + wv * 32 + mi * 16 + l15;
    bf16* dst = wa + (size_t)(b * SS + sq) * DIM + h * HD + quad * 4;
#pragma unroll
    for (int nd = 0; nd < 4; nd++) {
      uint2 pv;
      pv.x = pk2(O[mi][nd][0] * rln, O[mi][nd][1] * rln);
      pv.y = pk2(O[mi][nd][2] * rln, O[mi][nd][3] * rln);
      *(uint2*)&dst[nd * 16] = pv;
    }
  }
}

// ---------------------------------------------------------------------------
extern "C" void kernel_launch(void* const* d_in, const int* in_sizes, int n_in,
                              void* d_out, int out_size, void* d_ws,
                              size_t ws_size, hipStream_t stream) {
  const float* x = (const float*)d_in[0];
  const int* mask = (const int*)d_in[1];
  const float* w_qkv = (const float*)d_in[2];
  const float* b_qkv = (const float*)d_in[3];
  const float* w_proj = (const float*)d_in[4];
  const float* b_proj = (const float*)d_in[5];
  const float* g1 = (const float*)d_in[6];
  const float* beta1 = (const float*)d_in[7];
  const float* g2 = (const float*)d_in[8];
  const float* beta2 = (const float*)d_in[9];
  const float* w1 = (const float*)d_in[10];
  const float* b1 = (const float*)d_in[11];
  const float* w2 = (const float*)d_in[12];
  const float* b2 = (const float*)d_in[13];
  float* out = (float*)d_out;

  char* p = (char*)d_ws;
  auto alloc = [&](size_t bytes) {
    char* r = p;
    p += (bytes + 1023) & ~(size_t)1023;
    return r;
  };
  bf16* wqkvT = (bf16*)alloc((size_t)2304 * 768 * 2);
  bf16* wprojT = (bf16*)alloc((size_t)768 * 768 * 2);
  bf16* w1T = (bf16*)alloc((size_t)3072 * 768 * 2);
  bf16* w2T = (bf16*)alloc((size_t)768 * 3072 * 2);
  unsigned* bits = (unsigned*)alloc((size_t)BB * SS * 64 * 4);
  bf16* h = (bf16*)alloc((size_t)8192 * 768 * 2);
  bf16* qb = (bf16*)alloc((size_t)8192 * 768 * 2);
  bf16* kb = (bf16*)alloc((size_t)8192 * 768 * 2);
  bf16* vtb = (bf16*)alloc((size_t)8192 * 768 * 2);
  bf16* wab = (bf16*)alloc((size_t)8192 * 768 * 2);
  float* x2 = (float*)alloc((size_t)8192 * 768 * 4);
  bf16* ffn1 = (bf16*)alloc((size_t)8192 * 3072 * 2);

  // fused weight cast+transpose (one launch)
  castT_all_kernel<<<6912, 256, 0, stream>>>(w_qkv, wqkvT, w_proj, wprojT, w1,
                                             w1T, w2, w2T);
  // mask -> bits
  maskbits_kernel<<<(BB * SS * SS) / 256, 256, 0, stream>>>(mask, bits);
  // LN1
  ln_kernel<<<8192, 256, 0, stream>>>(x, g1, beta1, h);
  // QKV (V written pre-transposed, Q pre-scaled)
  gemm_kernel<EPI_QKV, 768, 128>
      <<<dim3(2304 / 128, 8192 / 128), 256, 0, stream>>>(h, wqkvT, b_qkv,
                                                         nullptr, qb, kb, vtb);
  // attention (128 q-rows per block)
  attn_kernel<<<dim3(SS / 128, NH, BB), 256, 0, stream>>>(qb, kb, vtb, bits,
                                                          wab);
  // proj + residual (TN=64 -> 768 blocks)
  gemm_kernel<EPI_PROJ, 768, 64>
      <<<dim3(768 / 64, 8192 / 128), 256, 0, stream>>>(wab, wprojT, b_proj, x,
                                                       x2, nullptr, nullptr);
  // LN2
  ln_kernel<<<8192, 256, 0, stream>>>(x2, g2, beta2, h);
  // FFN1 + GELU
  gemm_kernel<EPI_FFN1, 768, 128>
      <<<dim3(3072 / 128, 8192 / 128), 256, 0, stream>>>(h, w1T, b1, nullptr,
                                                         ffn1, nullptr,
                                                         nullptr);
  // FFN2 + residual -> out (TN=64 -> 768 blocks)
  gemm_kernel<EPI_FFN2, 3072, 64>
      <<<dim3(768 / 64, 8192 / 128), 256, 0, stream>>>(ffn1, w2T, b2, x2, out,
                                                       nullptr, nullptr);
}

// Round 9
// 494.111 us; speedup vs baseline: 1.0703x; 1.0223x over previous
//
#include <hip/hip_runtime.h>
#include <hip/hip_bf16.h>
#include <math.h>

typedef __bf16 bf16;
typedef __bf16 bf16x8 __attribute__((ext_vector_type(8)));
typedef short bf16x4s __attribute__((ext_vector_type(4)));
typedef float f32x4 __attribute__((ext_vector_type(4)));

#define DIM 768
#define NH 12
#define HD 64
#define HID 3072
#define BB 4
#define SS 2048
#define QPRESCALE 0.18033688011112042f /* (1/8) * log2(e) */

#define MFMA(a, b, c) __builtin_amdgcn_mfma_f32_16x16x32_bf16(a, b, c, 0, 0, 0)
#define MFMA16(a, b, c) \
  __builtin_amdgcn_mfma_f32_16x16x16bf16_1k(a, b, c, 0, 0, 0)

__device__ __forceinline__ void gld16(const void* g, void* l) {
  __builtin_amdgcn_global_load_lds(
      (const __attribute__((address_space(1))) void*)g,
      (__attribute__((address_space(3))) void*)l, 16, 0, 0);
}

__device__ __forceinline__ unsigned pk2(float a, float b) {
  union {
    bf16 h[2];
    unsigned u;
  } t;
  t.h[0] = (bf16)a;
  t.h[1] = (bf16)b;
  return t.u;
}

// ---------------- fused weight cast + transpose: fp32 [R][C] -> bf16 [C][R] -
__global__ __launch_bounds__(256) void castT_all_kernel(
    const float* __restrict__ s0, bf16* __restrict__ d0,
    const float* __restrict__ s1, bf16* __restrict__ d1,
    const float* __restrict__ s2, bf16* __restrict__ d2,
    const float* __restrict__ s3, bf16* __restrict__ d3) {
  __shared__ float tile[32][33];
  int id = blockIdx.x;
  const float* in;
  bf16* out;
  int R, C, loc;
  if (id < 1728) { in = s0; out = d0; R = 768; C = 2304; loc = id; }
  else if (id < 2304) { in = s1; out = d1; R = 768; C = 768; loc = id - 1728; }
  else if (id < 4608) { in = s2; out = d2; R = 768; C = 3072; loc = id - 2304; }
  else { in = s3; out = d3; R = 3072; C = 768; loc = id - 4608; }
  const int cb = C >> 5;
  const int c0 = (loc % cb) * 32, r0 = (loc / cb) * 32;
  const int tx = threadIdx.x & 31, ty = threadIdx.x >> 5;  // ty 0..7
#pragma unroll
  for (int i = 0; i < 32; i += 8)
    tile[ty + i][tx] = in[(size_t)(r0 + ty + i) * C + c0 + tx];
  __syncthreads();
#pragma unroll
  for (int i = 0; i < 32; i += 8)
    out[(size_t)(c0 + ty + i) * R + r0 + tx] = (bf16)tile[tx][ty + i];
}

// ---------------- mask int32 [B][1][S][S] -> bitmask [B][S][S/32] ----------
__global__ __launch_bounds__(256) void maskbits_kernel(
    const int* __restrict__ mask, unsigned* __restrict__ bits) {
  const int i = blockIdx.x * 256 + threadIdx.x;
  unsigned long long m = __ballot(mask[i] != 0);
  const int lane = threadIdx.x & 63;
  if (lane == 0) bits[i >> 5] = (unsigned)m;
  else if (lane == 32) bits[i >> 5] = (unsigned)(m >> 32);
}

// ---------------- LayerNorm fp32 row(768) -> bf16 --------------------------
__global__ __launch_bounds__(256) void ln_kernel(
    const float* __restrict__ x, const float* __restrict__ g,
    const float* __restrict__ beta, bf16* __restrict__ out) {
  const int row = blockIdx.x, t = threadIdx.x;
  const float* xr = x + (size_t)row * DIM;
  float v0 = xr[t], v1 = xr[t + 256], v2 = xr[t + 512];
  float s = v0 + v1 + v2;
  float s2 = v0 * v0 + v1 * v1 + v2 * v2;
#pragma unroll
  for (int d = 1; d < 64; d <<= 1) {
    s += __shfl_xor(s, d);
    s2 += __shfl_xor(s2, d);
  }
  __shared__ float red[8];
  const int wv = t >> 6, lane = t & 63;
  if (lane == 0) { red[wv] = s; red[wv + 4] = s2; }
  __syncthreads();
  s = red[0] + red[1] + red[2] + red[3];
  s2 = red[4] + red[5] + red[6] + red[7];
  const float mu = s * (1.0f / DIM);
  const float var = s2 * (1.0f / DIM) - mu * mu;
  const float r = rsqrtf(var + 1e-6f);
  bf16* o = out + (size_t)row * DIM;
  o[t] = (bf16)((v0 - mu) * r * g[t] + beta[t]);
  o[t + 256] = (bf16)((v1 - mu) * r * g[t + 256] + beta[t + 256]);
  o[t + 512] = (bf16)((v2 - mu) * r * g[t + 512] + beta[t + 512]);
}

// ---------------- GEMM: A[M][K] bf16 x Bt[N][K] bf16 -> epilogue -----------
// TM=128, TN=64: 4 waves of 32x64. acc = 2x4 f32x4 (32 AGPR) -> ~124 unified
// regs -> 4+ waves/SIMD. Double-buffered LDS (48 KB, 3 blocks/CU), ONE
// barrier per iter; stage(next) issued AFTER the barrier into buf^1 (any
// wave's prior reads of that buffer drained at the barrier it just crossed),
// so the barrier's vmcnt(0) only drains DMAs issued one compute-phase ago.
enum { EPI_QKV = 0, EPI_PROJ = 1, EPI_FFN1 = 2, EPI_FFN2 = 3 };

template <int EPI, int K>
__global__ __launch_bounds__(256) void gemm_kernel(
    const bf16* __restrict__ A, const bf16* __restrict__ Bt,
    const float* __restrict__ bias, const float* __restrict__ res,
    void* __restrict__ o0, void* __restrict__ o1, void* __restrict__ o2) {
  constexpr int NIT = K / 64;
  __shared__ bf16 As[2][128 * 64];
  __shared__ bf16 Bs[2][64 * 64];
  const int tid = threadIdx.x;
  const int wv = tid >> 6, lane = tid & 63;
  const int quad = lane >> 4, l15 = lane & 15;
  const int lrow = lane >> 3, lcol = lane & 7;
  const int m0 = blockIdx.y * 128, n0 = blockIdx.x * 64;
  const int wm = wv * 32;

  f32x4 acc[2][4] = {};

  // staging: lane -> row lrow, slot lcol ; swizzled global chunk = lcol^lrow
  const int swz = (lcol ^ lrow) * 8;
  const bf16* Ag = A + (size_t)(m0 + wv * 32 + lrow) * K + swz;
  const bf16* Bg = Bt + (size_t)(n0 + wv * 16 + lrow) * K + swz;

  auto stage = [&](int buf, int k0) {
#pragma unroll
    for (int i = 0; i < 4; i++)
      gld16(Ag + (size_t)(i * 8) * K + k0, &As[buf][(wv * 32 + i * 8) * 64]);
#pragma unroll
    for (int i = 0; i < 2; i++)
      gld16(Bg + (size_t)(i * 8) * K + k0,
            &Bs[buf][(wv * 16 + i * 8) * 64]);
  };

  stage(0, 0);

  for (int it = 0; it < NIT; ++it) {
    __syncthreads();  // drains this iter's DMAs (issued one compute ago)
    if (it + 1 < NIT) stage((it + 1) & 1, (it + 1) * 64);
    const bf16* Ab = As[it & 1];
    const bf16* Bb = Bs[it & 1];
#pragma unroll
    for (int ks = 0; ks < 2; ks++) {
      bf16x8 af[2], bfr[4];
#pragma unroll
      for (int i = 0; i < 2; i++) {
        const int ra = wm + i * 16 + l15;
        af[i] = *(const bf16x8*)&Ab[ra * 64 + ((ks * 4 + quad) ^ (ra & 7)) * 8];
      }
#pragma unroll
      for (int i = 0; i < 4; i++) {
        const int rb = i * 16 + l15;
        bfr[i] =
            *(const bf16x8*)&Bb[rb * 64 + ((ks * 4 + quad) ^ (rb & 7)) * 8];
      }
#pragma unroll
      for (int mi = 0; mi < 2; mi++)
#pragma unroll
        for (int ni = 0; ni < 4; ni++)
          acc[mi][ni] = MFMA(af[mi], bfr[ni], acc[mi][ni]);
    }
  }

  // epilogue: C layout col=lane&15, row=quad*4+reg
#pragma unroll
  for (int mi = 0; mi < 2; mi++) {
#pragma unroll
    for (int ni = 0; ni < 4; ni++) {
      const int n = n0 + ni * 16 + l15;
      const float bv = bias[n];
      const int mb = m0 + wm + mi * 16 + quad * 4;
      float val[4];
#pragma unroll
      for (int r = 0; r < 4; r++) val[r] = acc[mi][ni][r] + bv;
      if (EPI == EPI_QKV) {
        const int which = n / 768;
        const int nn = n - which * 768;
        const int hh = nn >> 6, d = nn & 63;
        const int bb = mb >> 11, s = mb & 2047;
        if (which == 0) {
#pragma unroll
          for (int r = 0; r < 4; r++)
            ((bf16*)o0)[((size_t)(bb * NH + hh) * SS + s + r) * HD + d] =
                (bf16)(val[r] * QPRESCALE);
        } else if (which == 1) {
#pragma unroll
          for (int r = 0; r < 4; r++)
            ((bf16*)o1)[((size_t)(bb * NH + hh) * SS + s + r) * HD + d] =
                (bf16)val[r];
        } else {
          // V transposed [bh][d][s]: 4 consecutive s -> packed 8B store
          uint2 pv;
          pv.x = pk2(val[0], val[1]);
          pv.y = pk2(val[2], val[3]);
          *(uint2*)&((bf16*)o2)[((size_t)(bb * NH + hh) * HD + d) * SS + s] = pv;
        }
      } else if (EPI == EPI_PROJ) {
#pragma unroll
        for (int r = 0; r < 4; r++)
          ((float*)o0)[(size_t)(mb + r) * DIM + n] =
              res[(size_t)(mb + r) * DIM + n] + val[r];
      } else if (EPI == EPI_FFN1) {
#pragma unroll
        for (int r = 0; r < 4; r++) {
          const float ge =
              0.5f * val[r] * (1.0f + erff(val[r] * 0.70710678118654752f));
          ((bf16*)o0)[(size_t)(mb + r) * HID + n] = (bf16)ge;
        }
      } else {  // EPI_FFN2
#pragma unroll
        for (int r = 0; r < 4; r++)
          ((float*)o0)[(size_t)(mb + r) * DIM + n] =
              res[(size_t)(mb + r) * DIM + n] + val[r];
      }
    }
  }
}

// ---------------- flash attention ------------------------------------------
// Sᵀ = MFMA(kfrag, qfrag) -> C layout (col=q, row=k) IS mfma16's B-frag
// layout, so PV needs no P movement. lsum via ones-A MFMA16 (row-sum of P).
// Mask via 16-entry LDS LUT on packed P. 128 q-rows per block (2 q-frags per
// wave) so each wave's full K/V-tile LDS re-read is amortized over 2x FLOPs.
__global__ __launch_bounds__(256) void attn_kernel(
    const bf16* __restrict__ q, const bf16* __restrict__ k,
    const bf16* __restrict__ vT, const unsigned* __restrict__ bits,
    bf16* __restrict__ wa) {
  const int b = blockIdx.z, h = blockIdx.y, q0 = blockIdx.x * 128;
  const int tid = threadIdx.x, wv = tid >> 6, lane = tid & 63;
  const int quad = lane >> 4, l15 = lane & 15;
  const int lrow = lane >> 3, lcol = lane & 7;

  __shared__ bf16 Ks[64 * 64];
  __shared__ bf16 Vs[64 * 64];
  __shared__ unsigned lut[32];

  if (tid < 16) {
    lut[2 * tid] =
        ((tid & 1) ? 0xFFFFu : 0u) | ((tid & 2) ? 0xFFFF0000u : 0u);
    lut[2 * tid + 1] =
        ((tid & 4) ? 0xFFFFu : 0u) | ((tid & 8) ? 0xFFFF0000u : 0u);
  }

  const bf16* qbh = q + (size_t)(b * NH + h) * SS * HD;
  const bf16* kbh = k + (size_t)(b * NH + h) * SS * HD;
  const bf16* vbh = vT + (size_t)(b * NH + h) * HD * SS;

  // Q fragments (B-operand for Sᵀ): q-row = q0 + wv*32 + mi*16 + l15
  bf16x8 aq[2][2];
#pragma unroll
  for (int mi = 0; mi < 2; mi++)
#pragma unroll
    for (int ks = 0; ks < 2; ks++) {
      const int s = q0 + wv * 32 + mi * 16 + l15;
      aq[mi][ks] = *(const bf16x8*)&qbh[(size_t)s * HD + ks * 32 + quad * 8];
    }

  const unsigned long long* mrow[2];
#pragma unroll
  for (int mi = 0; mi < 2; mi++)
    mrow[mi] = (const unsigned long long*)bits +
               (size_t)(b * SS + q0 + wv * 32 + mi * 16 + l15) * 32;

  f32x4 O[2][4] = {};
  f32x4 lm[2] = {};
  const short oneb = 0x3F80;
  const bf16x4s onesA = {oneb, oneb, oneb, oneb};
  const int swz = (lcol ^ lrow) * 8;

  for (int t = 0; t < SS / 64; ++t) {
    const int s0 = t * 64;
    // stage K[s0..+64][0..64] and Vᵀ[0..64][s0..+64] (XOR-chunk swizzle)
#pragma unroll
    for (int i = 0; i < 2; i++) {
      const int r = wv * 16 + i * 8 + lrow;
      gld16(&kbh[(size_t)(s0 + r) * HD + swz], &Ks[(wv * 16 + i * 8) * 64]);
      gld16(&vbh[(size_t)r * SS + s0 + swz], &Vs[(wv * 16 + i * 8) * 64]);
    }
    const unsigned long long sh0 = mrow[0][t] >> (quad * 4);
    const unsigned long long sh1 = mrow[1][t] >> (quad * 4);
    const unsigned lo0 = (unsigned)sh0, hi0 = (unsigned)(sh0 >> 32);
    const unsigned lo1 = (unsigned)sh1, hi1 = (unsigned)(sh1 >> 32);
    __syncthreads();

#pragma unroll
    for (int ni = 0; ni < 4; ni++) {
      const int rr = ni * 16 + l15;
      const bf16x8 kf0 = *(const bf16x8*)&Ks[rr * 64 + (quad ^ (rr & 7)) * 8];
      const bf16x8 kf1 =
          *(const bf16x8*)&Ks[rr * 64 + ((4 + quad) ^ (rr & 7)) * 8];
      f32x4 a0 = {}, a1 = {};
      a0 = MFMA(kf0, aq[0][0], a0);
      a0 = MFMA(kf1, aq[0][1], a0);
      a1 = MFMA(kf0, aq[1][0], a1);
      a1 = MFMA(kf1, aq[1][1], a1);
      const unsigned nib0 = (ni == 0)   ? (lo0 & 0xF)
                            : (ni == 1) ? ((lo0 >> 16) & 0xF)
                            : (ni == 2) ? (hi0 & 0xF)
                                        : ((hi0 >> 16) & 0xF);
      const unsigned nib1 = (ni == 0)   ? (lo1 & 0xF)
                            : (ni == 1) ? ((lo1 >> 16) & 0xF)
                            : (ni == 2) ? (hi1 & 0xF)
                                        : ((hi1 >> 16) & 0xF);
      const uint2 mw0 = *(const uint2*)&lut[2 * nib0];
      const uint2 mw1 = *(const uint2*)&lut[2 * nib1];
      union {
        unsigned u[2];
        bf16x4s v;
      } p0, p1;
      p0.u[0] = pk2(__builtin_amdgcn_exp2f(a0[0]),
                    __builtin_amdgcn_exp2f(a0[1])) & mw0.x;
      p0.u[1] = pk2(__builtin_amdgcn_exp2f(a0[2]),
                    __builtin_amdgcn_exp2f(a0[3])) & mw0.y;
      p1.u[0] = pk2(__builtin_amdgcn_exp2f(a1[0]),
                    __builtin_amdgcn_exp2f(a1[1])) & mw1.x;
      p1.u[1] = pk2(__builtin_amdgcn_exp2f(a1[2]),
                    __builtin_amdgcn_exp2f(a1[3])) & mw1.y;
      lm[0] = MFMA16(onesA, p0.v, lm[0]);
      lm[1] = MFMA16(onesA, p1.v, lm[1]);
#pragma unroll
      for (int nd = 0; nd < 4; nd++) {
        const int row = nd * 16 + l15;
        const int pc = (ni * 2 + (quad >> 1)) ^ (row & 7);
        const bf16x4s vf =
            *(const bf16x4s*)&Vs[row * 64 + pc * 8 + (quad & 1) * 4];
        O[0][nd] = MFMA16(vf, p0.v, O[0][nd]);
        O[1][nd] = MFMA16(vf, p1.v, O[1][nd]);
      }
    }
    __syncthreads();
  }

  // lm[mi][r] (any r) = full softmax denominator for this lane's q-row
#pragma unroll
  for (int mi = 0; mi < 2; mi++) {
    const float rln = __builtin_amdgcn_rcpf(lm[mi][0]);
    const int sq = q0 + wv * 32 + mi * 16 + l15;
    bf16* dst = wa + (size_t)(b * SS + sq) * DIM + h * HD + quad * 4;
#pragma unroll
    for (int nd = 0; nd < 4; nd++) {
      uint2 pv;
      pv.x = pk2(O[mi][nd][0] * rln, O[mi][nd][1] * rln);
      pv.y = pk2(O[mi][nd][2] * rln, O[mi][nd][3] * rln);
      *(uint2*)&dst[nd * 16] = pv;
    }
  }
}

// ---------------------------------------------------------------------------
extern "C" void kernel_launch(void* const* d_in, const int* in_sizes, int n_in,
                              void* d_out, int out_size, void* d_ws,
                              size_t ws_size, hipStream_t stream) {
  const float* x = (const float*)d_in[0];
  const int* mask = (const int*)d_in[1];
  const float* w_qkv = (const float*)d_in[2];
  const float* b_qkv = (const float*)d_in[3];
  const float* w_proj = (const float*)d_in[4];
  const float* b_proj = (const float*)d_in[5];
  const float* g1 = (const float*)d_in[6];
  const float* beta1 = (const float*)d_in[7];
  const float* g2 = (const float*)d_in[8];
  const float* beta2 = (const float*)d_in[9];
  const float* w1 = (const float*)d_in[10];
  const float* b1 = (const float*)d_in[11];
  const float* w2 = (const float*)d_in[12];
  const float* b2 = (const float*)d_in[13];
  float* out = (float*)d_out;

  char* p = (char*)d_ws;
  auto alloc = [&](size_t bytes) {
    char* r = p;
    p += (bytes + 1023) & ~(size_t)1023;
    return r;
  };
  bf16* wqkvT = (bf16*)alloc((size_t)2304 * 768 * 2);
  bf16* wprojT = (bf16*)alloc((size_t)768 * 768 * 2);
  bf16* w1T = (bf16*)alloc((size_t)3072 * 768 * 2);
  bf16* w2T = (bf16*)alloc((size_t)768 * 3072 * 2);
  unsigned* bits = (unsigned*)alloc((size_t)BB * SS * 64 * 4);
  bf16* h = (bf16*)alloc((size_t)8192 * 768 * 2);
  bf16* qb = (bf16*)alloc((size_t)8192 * 768 * 2);
  bf16* kb = (bf16*)alloc((size_t)8192 * 768 * 2);
  bf16* vtb = (bf16*)alloc((size_t)8192 * 768 * 2);
  bf16* wab = (bf16*)alloc((size_t)8192 * 768 * 2);
  float* x2 = (float*)alloc((size_t)8192 * 768 * 4);
  bf16* ffn1 = (bf16*)alloc((size_t)8192 * 3072 * 2);

  // fused weight cast+transpose (one launch)
  castT_all_kernel<<<6912, 256, 0, stream>>>(w_qkv, wqkvT, w_proj, wprojT, w1,
                                             w1T, w2, w2T);
  // mask -> bits
  maskbits_kernel<<<(BB * SS * SS) / 256, 256, 0, stream>>>(mask, bits);
  // LN1
  ln_kernel<<<8192, 256, 0, stream>>>(x, g1, beta1, h);
  // QKV (V written pre-transposed, Q pre-scaled)
  gemm_kernel<EPI_QKV, 768>
      <<<dim3(2304 / 64, 8192 / 128), 256, 0, stream>>>(h, wqkvT, b_qkv,
                                                        nullptr, qb, kb, vtb);
  // attention (128 q-rows per block)
  attn_kernel<<<dim3(SS / 128, NH, BB), 256, 0, stream>>>(qb, kb, vtb, bits,
                                                          wab);
  // proj + residual
  gemm_kernel<EPI_PROJ, 768>
      <<<dim3(768 / 64, 8192 / 128), 256, 0, stream>>>(wab, wprojT, b_proj, x,
                                                       x2, nullptr, nullptr);
  // LN2
  ln_kernel<<<8192, 256, 0, stream>>>(x2, g2, beta2, h);
  // FFN1 + GELU
  gemm_kernel<EPI_FFN1, 768>
      <<<dim3(3072 / 64, 8192 / 128), 256, 0, stream>>>(h, w1T, b1, nullptr,
                                                        ffn1, nullptr,
                                                        nullptr);
  // FFN2 + residual -> out
  gemm_kernel<EPI_FFN2, 3072>
      <<<dim3(768 / 64, 8192 / 128), 256, 0, stream>>>(ffn1, w2T, b2, x2, out,
                                                       nullptr, nullptr);
}